// Round 11
// baseline (3356.756 us; speedup 1.0000x reference)
//
#include <hip/hip_runtime.h>

#define NTOT   2048
#define BATCH  32
#define TSTEPS 500
#define NBLK   256               // 1 block/CU — proven launch/barrier scale
#define COLS   8                 // columns per block
#define CAP    320               // CSR capacity/col (nnz ~ Binom(2048,0.1): max ~265)
#define RELEMS (BATCH * NTOT)    // 65536
#define OUT_BASE (TSTEPS * RELEMS)
#define NGRP   8                 // barrier groups of 32 blocks
#define GRPSZ  32
#define GLOBI  128               // global counter slot; group g at bar[16*g]

static __device__ __forceinline__ float act(float u) {
  return 1.0f / (1.0f + expf(2.0f - 3.0f * u));   // sigmoid(3u-2), round-5-validated
}
// Coherent (LLC-backed) access — producers always publish through LLC.
static __device__ __forceinline__ void st_coh(float* p, float v) {
  __hip_atomic_store(p, v, __ATOMIC_RELAXED, __HIP_MEMORY_SCOPE_AGENT);
}
static __device__ __forceinline__ float ld_coh(const float* p) {
  return __hip_atomic_load(p, __ATOMIC_RELAXED, __HIP_MEMORY_SCOPE_AGENT);
}

__global__ void alif_init(unsigned int* bar) { bar[threadIdx.x] = 0u; }  // 256 words

// FRESH=true: rbuf advances through TSTEPS+1 phases -> plain cached gathers are safe
// (no stale line can exist; L2 serves the ~32x per-XCD reuse). FRESH=false: 2-phase
// rbuf + agent-scope gathers (round-9 behavior).
template <bool FRESH>
__global__ __launch_bounds__(1024, 4) void alif_main(
    const float* __restrict__ u0,
    const float* __restrict__ ext,
    const float* __restrict__ wrec,
    const float* __restrict__ mask,
    const float* __restrict__ sign,
    const float* __restrict__ dtv,
    float* __restrict__ rbuf,            // [nph][NTOT][BATCH] f32 (transposed r)
    float* __restrict__ usave,           // d_out (f32)
    unsigned int* __restrict__ bar) {
  const int tid  = threadIdx.x;
  const int lane = tid & 63;
  const int wv   = tid >> 6;
  const int nw   = blockDim.x >> 6;      // 16 (or 4 in fallback)
  const int KR   = NTOT / nw;            // k-range per wave in CSR build
  const int S    = nw;                   // k-slices per column (16 or 4)

  __shared__ uint2  csr[COLS * CAP];     // 20 KB: (.x = f32 weight bits, .y = k*BATCH)
  __shared__ float4 red4[128][8];        // 16 KB: [group][lane8] float4 partials
  __shared__ int    wcnt[16];
  __shared__ int    nnzs[COLS];
  __shared__ int    Lcol[COLS];          // per-column padded length (mult of 4*S)

  // ---- build CSR once: all waves cooperate per column (two-pass count+write) ----
  for (int clb = 0; clb < COLS; ++clb) {
    const int c = blockIdx.x * COLS + clb;
    const float* __restrict__ mrow = mask + c * NTOT;
    int cnt = 0;
    for (int k0 = wv * KR; k0 < wv * KR + KR; k0 += 64)
      cnt += __popcll(__ballot(mrow[k0 + lane] != 0.0f));
    if (lane == 0) wcnt[wv] = cnt;
    __syncthreads();
    int base = 0, total = 0;
    for (int w2 = 0; w2 < nw; ++w2) {
      if (w2 < wv) base += wcnt[w2];
      total += wcnt[w2];
    }
    for (int k0 = wv * KR; k0 < wv * KR + KR; k0 += 64) {
      const int k = k0 + lane;
      const float mv = mrow[k];
      const bool nz = (mv != 0.0f);
      const unsigned long long bal = __ballot(nz);
      if (nz) {
        const int pos = base + __popcll(bal & ((1ull << lane) - 1ull));
        const float w = mv * fmaxf(wrec[c * NTOT + k], 0.0f) * sign[k];  // exact f32
        if (pos < CAP) csr[clb * CAP + pos] = make_uint2(__float_as_uint(w), (unsigned)(k * BATCH));
      }
      base += __popcll(bal);
    }
    if (tid == 0) {
      const int nn = (total < CAP) ? total : CAP;
      nnzs[clb] = nn;
      const int padm = 4 * S;            // 64 (or 16): L = Lcol/S stays mult of 4
      Lcol[clb] = (nn + padm - 1) & ~(padm - 1);
    }
    __syncthreads();                     // wcnt reuse + nnzs/Lcol visibility
  }
  for (int clb = 0; clb < COLS; ++clb)   // zero-pad: fmaf(r,0,acc) exact no-op
    for (int i = nnzs[clb] + tid; i < Lcol[clb]; i += blockDim.x)
      csr[clb * CAP + i] = make_uint2(0u, 0u);
  // pad-writes ordered before first use by the t=0 barrier's __syncthreads

  // ---- roles: 8-thread groups; group = (slice s, col cl); lane8 covers 4 batches ----
  const int grp = tid >> 3;              // 0..127 (0..31 fallback)
  const int l8  = tid & 7;
  const int b0  = l8 * 4;                // batch quad
  const int cl  = grp & 7;
  const int s   = grp >> 3;              // 0..S-1
  const int c   = blockIdx.x * COLS + cl;
  const bool own = (s == 0);             // 64 owner threads, 4 (b,c) states each

  float4 u4 = {0.f, 0.f, 0.f, 0.f}, uprev = u4;
  float dtc = 0.f, omd = 0.f;
  if (own) {
    dtc = dtv[c];
    omd = 1.0f - dtc;
    u4.x = u0[(b0 + 0) * NTOT + c];
    u4.y = u0[(b0 + 1) * NTOT + c];
    u4.z = u0[(b0 + 2) * NTOT + c];
    u4.w = u0[(b0 + 3) * NTOT + c];
    float* r0p = rbuf + c * BATCH + b0;  // r_0 -> phase 0, write-through to LLC
    st_coh(r0p + 0, act(u4.x));
    st_coh(r0p + 1, act(u4.y));
    st_coh(r0p + 2, act(u4.z));
    st_coh(r0p + 3, act(u4.w));
  }
  const int g = blockIdx.x & (NGRP - 1);

  for (int t = 0; t < TSTEPS; ++t) {
    // ---- grid barrier, zero cache maintenance (round-9-proven) ----
    __syncthreads();                     // drains rbuf st_coh (usave acked long ago)
    if (tid == 0) {
      const unsigned prev =
          __hip_atomic_fetch_add(&bar[16 * g], 1u, __ATOMIC_RELAXED, __HIP_MEMORY_SCOPE_AGENT);
      if (((prev + 1u) & (GRPSZ - 1u)) == 0u)
        __hip_atomic_fetch_add(&bar[GLOBI], 1u, __ATOMIC_RELAXED, __HIP_MEMORY_SCOPE_AGENT);
      const unsigned gt = (unsigned)(t + 1) * NGRP;
      while (__hip_atomic_load(&bar[GLOBI], __ATOMIC_RELAXED, __HIP_MEMORY_SCOPE_AGENT) < gt)
        __builtin_amdgcn_s_sleep(1);
    }
    __syncthreads();

    // ---- early issues (owners): deferred usave[t-1] stores + ext[t] loads.
    //      Both ack/arrive under the dot; drained by NEXT loop-top syncthreads. ----
    float4 ev = {0.f, 0.f, 0.f, 0.f};
    if (own) {
      if (t > 0) {
        float* up = usave + (size_t)(t - 1) * RELEMS + c;
        up[(b0 + 0) * NTOT] = uprev.x;
        up[(b0 + 1) * NTOT] = uprev.y;
        up[(b0 + 2) * NTOT] = uprev.z;
        up[(b0 + 3) * NTOT] = uprev.w;
      }
      const float* ep = ext + (size_t)t * RELEMS + c;
      ev.x = ep[(b0 + 0) * NTOT];
      ev.y = ep[(b0 + 1) * NTOT];
      ev.z = ep[(b0 + 2) * NTOT];
      ev.w = ep[(b0 + 3) * NTOT];
    }

    // ---- exact-f32 sparse dot, slice s: one 128 B line per entry per 8-thread group ----
    const int Lc = Lcol[cl] / S;         // mult of 4
    const uint2* __restrict__ ce = csr + cl * CAP + s * Lc;
    const size_t rph = FRESH ? (size_t)t : (size_t)(t & 1);
    const float* __restrict__ rrow = rbuf + rph * RELEMS + b0;
    float4 a0 = {0,0,0,0}, a1 = {0,0,0,0}, a2 = {0,0,0,0}, a3 = {0,0,0,0};
    for (int i = 0; i < Lc; i += 4) {
      const uint2 e0 = ce[i], e1 = ce[i + 1], e2 = ce[i + 2], e3 = ce[i + 3];
      const float w0 = __uint_as_float(e0.x), w1 = __uint_as_float(e1.x);
      const float w2 = __uint_as_float(e2.x), w3 = __uint_as_float(e3.x);
      if (FRESH) {
        const float4 r0 = *reinterpret_cast<const float4*>(rrow + e0.y);
        const float4 r1 = *reinterpret_cast<const float4*>(rrow + e1.y);
        const float4 r2 = *reinterpret_cast<const float4*>(rrow + e2.y);
        const float4 r3 = *reinterpret_cast<const float4*>(rrow + e3.y);
        a0.x = fmaf(r0.x, w0, a0.x); a0.y = fmaf(r0.y, w0, a0.y);
        a0.z = fmaf(r0.z, w0, a0.z); a0.w = fmaf(r0.w, w0, a0.w);
        a1.x = fmaf(r1.x, w1, a1.x); a1.y = fmaf(r1.y, w1, a1.y);
        a1.z = fmaf(r1.z, w1, a1.z); a1.w = fmaf(r1.w, w1, a1.w);
        a2.x = fmaf(r2.x, w2, a2.x); a2.y = fmaf(r2.y, w2, a2.y);
        a2.z = fmaf(r2.z, w2, a2.z); a2.w = fmaf(r2.w, w2, a2.w);
        a3.x = fmaf(r3.x, w3, a3.x); a3.y = fmaf(r3.y, w3, a3.y);
        a3.z = fmaf(r3.z, w3, a3.z); a3.w = fmaf(r3.w, w3, a3.w);
      } else {
        a0.x = fmaf(ld_coh(rrow + e0.y + 0), w0, a0.x);
        a0.y = fmaf(ld_coh(rrow + e0.y + 1), w0, a0.y);
        a0.z = fmaf(ld_coh(rrow + e0.y + 2), w0, a0.z);
        a0.w = fmaf(ld_coh(rrow + e0.y + 3), w0, a0.w);
        a1.x = fmaf(ld_coh(rrow + e1.y + 0), w1, a1.x);
        a1.y = fmaf(ld_coh(rrow + e1.y + 1), w1, a1.y);
        a1.z = fmaf(ld_coh(rrow + e1.y + 2), w1, a1.z);
        a1.w = fmaf(ld_coh(rrow + e1.y + 3), w1, a1.w);
        a2.x = fmaf(ld_coh(rrow + e2.y + 0), w2, a2.x);
        a2.y = fmaf(ld_coh(rrow + e2.y + 1), w2, a2.y);
        a2.z = fmaf(ld_coh(rrow + e2.y + 2), w2, a2.z);
        a2.w = fmaf(ld_coh(rrow + e2.y + 3), w2, a2.w);
        a3.x = fmaf(ld_coh(rrow + e3.y + 0), w3, a3.x);
        a3.y = fmaf(ld_coh(rrow + e3.y + 1), w3, a3.y);
        a3.z = fmaf(ld_coh(rrow + e3.y + 2), w3, a3.z);
        a3.w = fmaf(ld_coh(rrow + e3.y + 3), w3, a3.w);
      }
    }
    float4 p;
    p.x = (a0.x + a1.x) + (a2.x + a3.x);
    p.y = (a0.y + a1.y) + (a2.y + a3.y);
    p.z = (a0.z + a1.z) + (a2.z + a3.z);
    p.w = (a0.w + a1.w) + (a2.w + a3.w);
    red4[grp][l8] = p;
    __syncthreads();

    // ---- epilogue (owners): cross-slice reduce + leaky integration ----
    if (own) {
      float4 rec = {0.f, 0.f, 0.f, 0.f};
      for (int j = 0; j < S; ++j) {
        const float4 v = red4[8 * j + cl][l8];
        rec.x += v.x; rec.y += v.y; rec.z += v.z; rec.w += v.w;
      }
      u4.x = u4.x * omd + ((rec.x + 0.5f) + ev.x) * dtc;
      u4.y = u4.y * omd + ((rec.y + 0.5f) + ev.y) * dtc;
      u4.z = u4.z * omd + ((rec.z + 0.5f) + ev.z) * dtc;
      u4.w = u4.w * omd + ((rec.w + 0.5f) + ev.w) * dtc;
      const size_t wph = FRESH ? (size_t)(t + 1) : (size_t)((t + 1) & 1);
      float* rp = rbuf + wph * RELEMS + c * BATCH + b0;
      st_coh(rp + 0, act(u4.x));          // critical-path publish via LLC
      st_coh(rp + 1, act(u4.y));
      st_coh(rp + 2, act(u4.z));
      st_coh(rp + 3, act(u4.w));
      uprev = u4;                          // usave deferred to next iteration
    }
    // red4 WAR protected by next iteration's barrier __syncthreads
  }
  if (own) {                               // final usave flush (t = TSTEPS-1)
    float* up = usave + (size_t)(TSTEPS - 1) * RELEMS + c;
    up[(b0 + 0) * NTOT] = uprev.x;
    up[(b0 + 1) * NTOT] = uprev.y;
    up[(b0 + 2) * NTOT] = uprev.z;
    up[(b0 + 3) * NTOT] = uprev.w;
  }
}

// ---- outsave[t][b][o] = act(u_t) @ wout, u_t = (t==0 ? u0 : usave[t-1]) ----
__global__ __launch_bounds__(256) void alif_readout(
    const float* __restrict__ u0,
    const float* __restrict__ usave,
    const float* __restrict__ wout,
    float* __restrict__ outs) {
  const int wg = blockIdx.x * 4 + (threadIdx.x >> 6);   // 0..15999 = (t,b)
  const int lane = threadIdx.x & 63;
  const int t = wg >> 5, b = wg & 31;
  float a0 = 0.f, a1 = 0.f;
  for (int k0 = 0; k0 < NTOT; k0 += 64) {
    const int k = k0 + lane;
    const float uv = (t == 0) ? u0[b * NTOT + k] : usave[(t - 1) * RELEMS + b * NTOT + k];
    const float r = act(uv);
    const float2 w2 = *(const float2*)(wout + k * 2);
    a0 = fmaf(r, w2.x, a0);
    a1 = fmaf(r, w2.y, a1);
  }
#pragma unroll
  for (int off = 32; off; off >>= 1) {
    a0 += __shfl_xor(a0, off, 64);
    a1 += __shfl_xor(a1, off, 64);
  }
  if (lane == 0) {
    outs[t * (BATCH * 2) + b * 2 + 0] = a0;
    outs[t * (BATCH * 2) + b * 2 + 1] = a1;
  }
}

extern "C" void kernel_launch(void* const* d_in, const int* in_sizes, int n_in,
                              void* d_out, int out_size, void* d_ws, size_t ws_size,
                              hipStream_t stream) {
  const float* u0   = (const float*)d_in[0];
  const float* ext  = (const float*)d_in[1];
  const float* wrec = (const float*)d_in[2];
  const float* mask = (const float*)d_in[3];
  const float* sign = (const float*)d_in[4];
  const float* wout = (const float*)d_in[5];
  const float* dtv  = (const float*)d_in[6];
  float* out = (float*)d_out;

  char* w = (char*)d_ws;
  unsigned int* bar  = (unsigned int*)w;                 // 1 KB (slots 16g, 128)
  float*        rbuf = (float*)(w + 1024);

  const size_t need = 1024 + (size_t)(TSTEPS + 1) * RELEMS * sizeof(float);  // ~125 MB
  const bool fresh = (ws_size >= need);

  alif_init<<<dim3(1), dim3(256), 0, stream>>>(bar);

  void* args[] = {(void*)&u0, (void*)&ext, (void*)&wrec, (void*)&mask, (void*)&sign,
                  (void*)&dtv, (void*)&rbuf, (void*)&out, (void*)&bar};

  const void* fn = fresh ? (const void*)alif_main<true> : (const void*)alif_main<false>;
  hipError_t err = hipLaunchCooperativeKernel(fn, dim3(NBLK), dim3(1024), args, 0, stream);
  if (err != hipSuccess) {
    (void)hipLaunchCooperativeKernel(fn, dim3(NBLK), dim3(256), args, 0, stream);
  }

  alif_readout<<<dim3(TSTEPS * BATCH / 4), dim3(256), 0, stream>>>(
      u0, out, wout, out + OUT_BASE);
}